// Round 9
// baseline (615.769 us; speedup 1.0000x reference)
//
#include <hip/hip_runtime.h>
#include <hip/hip_bf16.h>
#include <math.h>

// Problem constants
#define NB   8
#define NT   1024
#define NG   128
#define NS   1152      // NT + NG
#define NDIN 512
#define NDM  512
#define NH   8
#define NDH  64
#define NFF  2048
#define NL   2

typedef __attribute__((ext_vector_type(4))) float  floatx4;
typedef __attribute__((ext_vector_type(8))) short  shortx8;

__device__ __forceinline__ float gelu_f(float x) {
    float u = 1.5957691216057308f * (x + 0.044715f * x * x * x);
    return x / (1.0f + __expf(-u));
}

__device__ __forceinline__ void gload_lds16(const void* g, void* l) {
    __builtin_amdgcn_global_load_lds((const __attribute__((address_space(1))) unsigned int*)g,
                                     (__attribute__((address_space(3))) unsigned int*)l, 16, 0, 0);
}

__device__ __forceinline__ short f2bfs(float x) {
    __hip_bfloat16 h = __float2bfloat16(x);
    return *(short*)&h;
}
// truncating (RTZ) pack of two fp32 -> bf16x2; cheap (3 VALU ops), used only for P
__device__ __forceinline__ unsigned pack_bf2_rz(float a, float b) {
    unsigned au = *(unsigned*)&a, bu = *(unsigned*)&b;
    return (au >> 16) | (bu & 0xFFFF0000u);
}

// Bijective XCD-aware block swizzle (T1/m204).  [R5: 613->608.6 µs]
__device__ __forceinline__ void swzxy(int& bx, int& by, int gx, int gy) {
    const int nwg = gx * gy;
    int flat = by * gx + bx;
    if ((nwg & 7) == 0) flat = (flat & 7) * (nwg >> 3) + (flat >> 3);
    bx = flat % gx; by = flat / gx;
}

// ---------------- merged prep: rope table + feature transpose + all weight transposes ----------------
__device__ __forceinline__ void wtile(const float* __restrict__ src,
        __hip_bfloat16* __restrict__ dst, int K, int N, int i, int tid, short tile[32][33])
{
    const int gx = N / 32;
    const int n0 = (i % gx) * 32;
    const int k0 = (i / gx) * 32;
    {
        const int r = tid >> 3, c4 = (tid & 7) * 4;
        float4 v = *(const float4*)&src[(size_t)(k0 + r) * N + n0 + c4];
        tile[c4 + 0][r] = f2bfs(v.x);
        tile[c4 + 1][r] = f2bfs(v.y);
        tile[c4 + 2][r] = f2bfs(v.z);
        tile[c4 + 3][r] = f2bfs(v.w);
    }
    __syncthreads();
    {
        const int r = tid >> 3, c4 = (tid & 7) * 4;
        short* dp = (short*)dst + (size_t)(n0 + r) * K + k0 + c4;
        short4 v;
        v.x = tile[r][c4 + 0]; v.y = tile[r][c4 + 1];
        v.z = tile[r][c4 + 2]; v.w = tile[r][c4 + 3];
        *(short4*)dp = v;
    }
}

__global__ __launch_bounds__(256) void prep0_k(
        float2* __restrict__ tab,
        const float* __restrict__ features, float* __restrict__ featT,
        const float* W_in, const float* Wq, const float* Wk, const float* Wv,
        const float* Wo, const float* W1, const float* W2, const float* W_out,
        __hip_bfloat16* w_inT, __hip_bfloat16* wqkvT0, __hip_bfloat16* wqkvT1,
        __hip_bfloat16* woT0, __hip_bfloat16* woT1,
        __hip_bfloat16* w1T0, __hip_bfloat16* w1T1,
        __hip_bfloat16* w2T0, __hip_bfloat16* w2T1, __hip_bfloat16* woutT)
{
    __shared__ __align__(16) char smem[32 * 33 * 4];
    const int tid = threadIdx.x;
    const int blk = blockIdx.x;
    if (blk < 144) {
        // rope cos/sin table
        const int idx = blk * 256 + tid;     // < 36864 = NS*32
        const int s = idx >> 5, i = idx & 31;
        const float fr = __expf(-(float)i * 0.28782313662425576f);
        const float ang = (float)s * fr;
        tab[idx] = make_float2(cosf(ang), sinf(ang));
    } else if (blk < 144 + 4096) {
        // features [b][d][t] -> featT [b][t][d]
        float (*tile)[33] = (float(*)[33])smem;
        const int v = blk - 144;
        const int t0 = (v & 31) * 32;
        const int d0 = ((v >> 5) & 15) * 32;
        const int b  = v >> 9;
        const int r = tid >> 3, c4 = (tid & 7) * 4;
        {
            float4 w = *(const float4*)&features[((size_t)(b * NDIN + d0 + r)) * NT + t0 + c4];
            tile[c4 + 0][r] = w.x; tile[c4 + 1][r] = w.y;
            tile[c4 + 2][r] = w.z; tile[c4 + 3][r] = w.w;
        }
        __syncthreads();
        {
            float4 w;
            w.x = tile[r][c4 + 0]; w.y = tile[r][c4 + 1];
            w.z = tile[r][c4 + 2]; w.w = tile[r][c4 + 3];
            *(float4*)&featT[((size_t)(b * NT + t0 + r)) * NDIN + d0 + c4] = w;
        }
    } else {
        // weight transposes
        short (*tile)[33] = (short(*)[33])smem;
        const int i = blk - (144 + 4096);    // < 6656
        const float* src; __hip_bfloat16* dst; int K, N, ti;
        if (i < 256) { src = W_in; dst = w_inT; K = 512; N = 512; ti = i; }
        else if (i < 6400) {
            int r = i - 256;
            const int l = r / 3072; r -= l * 3072;
            const size_t o5 = (size_t)l * 262144, o2 = (size_t)l * 1048576;
            if (r < 256)       { src = Wq + o5; dst = (l ? wqkvT1 : wqkvT0);          K = 512;  N = 512;  ti = r; }
            else if (r < 512)  { src = Wk + o5; dst = (l ? wqkvT1 : wqkvT0) + 262144; K = 512;  N = 512;  ti = r - 256; }
            else if (r < 768)  { src = Wv + o5; dst = (l ? wqkvT1 : wqkvT0) + 524288; K = 512;  N = 512;  ti = r - 512; }
            else if (r < 1024) { src = Wo + o5; dst = (l ? woT1 : woT0);              K = 512;  N = 512;  ti = r - 768; }
            else if (r < 2048) { src = W1 + o2; dst = (l ? w1T1 : w1T0);              K = 512;  N = 2048; ti = r - 1024; }
            else               { src = W2 + o2; dst = (l ? w2T1 : w2T0);              K = 2048; N = 512;  ti = r - 2048; }
        }
        else { src = W_out; dst = woutT; K = 512; N = 512; ti = i - 6400; }
        wtile(src, dst, K, N, ti, tid, tile);
    }
}

// ---------------- merged group-pool: stats + mean-pooled queries (featT, coalesced) ----------------
__global__ __launch_bounds__(256) void pool_k(const float* __restrict__ align,
        const float* __restrict__ featT, int* __restrict__ glast,
        float* __restrict__ queries)
{
    __shared__ float redf[256];
    __shared__ int   redi[256];
    __shared__ float aw[NT];
    const int bg = blockIdx.x;           // b*NG + g
    const int b = bg >> 7;
    const int tid = threadIdx.x;
    const float* arow = align + (size_t)bg * NT;
    float cnt = 0.f, last = 0.f;
    int tmin = NT;
    for (int t = tid; t < NT; t += 256) {
        float a = arow[t];
        cnt += a;
        last = fmaxf(last, a * (float)t);
        if (a > 0.f) tmin = min(tmin, t);
    }
    redf[tid] = cnt; __syncthreads();
    for (int s = 128; s > 0; s >>= 1) { if (tid < s) redf[tid] += redf[tid + s]; __syncthreads(); }
    float c = redf[0]; __syncthreads();
    redf[tid] = last; __syncthreads();
    for (int s = 128; s > 0; s >>= 1) { if (tid < s) redf[tid] = fmaxf(redf[tid], redf[tid + s]); __syncthreads(); }
    float l = redf[0];
    redi[tid] = tmin; __syncthreads();
    for (int s = 128; s > 0; s >>= 1) { if (tid < s) redi[tid] = min(redi[tid], redi[tid + s]); __syncthreads(); }
    const int t0 = redi[0];
    const int t1 = (int)l;
    if (tid == 0) glast[bg] = t1;
    __syncthreads();
    for (int t = t0 + tid; t <= t1; t += 256) aw[t - t0] = arow[t];
    __syncthreads();
    const float invc = 1.0f / fmaxf(c, 1.0f);
    const float* fT = featT + (size_t)b * NT * NDIN;
    for (int d = tid; d < NDIN; d += 256) {
        float s = 0.f;
        for (int t = t0; t <= t1; ++t) s += aw[t - t0] * fT[(size_t)t * NDIN + d];
        queries[(size_t)bg * NDIN + d] = s * invc;
    }
}

// ---------------- stable-argsort rank ----------------
__global__ __launch_bounds__(256) void rank_k(const int* __restrict__ glast,
        const int* __restrict__ nsegp, int* __restrict__ perm, int* __restrict__ qpos)
{
    __shared__ int dm[NS];
    __shared__ int gl[NG];
    const int b = blockIdx.y;
    const int tid = threadIdx.x;
    const int j = blockIdx.x * 256 + tid;
    if (tid < NG) gl[tid] = glast[b * NG + tid];
    const int ns = nsegp[b];
    __syncthreads();
    for (int jj = tid; jj < NS; jj += 256) {
        int d;
        if (jj < NT) {
            int t = jj, nq = 0, flen = 0;
            for (int g = 0; g < ns; ++g) {
                flen = max(flen, gl[g] + 1);
                nq += (gl[g] < t) ? 1 : 0;
            }
            d = (t < flen) ? (t + nq) : NS;
        } else {
            int g = jj - NT;
            d = (g < ns) ? (gl[g] + g + 1) : NS;
        }
        dm[jj] = d;
    }
    __syncthreads();
    if (j < NS) {
        const int my = dm[j];
        int r = 0;
        for (int t = 0; t < NS; ++t) {
            int v2 = dm[t];
            r += (v2 < my || (v2 == my && t < j)) ? 1 : 0;
        }
        perm[b * NS + r] = j;
        if (j >= NT) qpos[b * NG + (j - NT)] = r;
    }
}

// ---------------- build transformer input X (bf16, float4-vectorized, coalesced) ----------------
__global__ __launch_bounds__(256) void buildx_k(const float* __restrict__ featT,
        const float* __restrict__ queries, const int* __restrict__ perm,
        __hip_bfloat16* __restrict__ X)
{
    const int idx = blockIdx.x * 256 + threadIdx.x;    // NB*NS*(NDIN/4)
    if (idx >= NB * NS * (NDIN / 4)) return;
    const int dq = idx & 127;
    const int p = (idx >> 7) % NS;
    const int b = idx / (NS * 128);
    const int j = perm[b * NS + p];
    const float4* src = (j < NT)
        ? (const float4*)&featT[((size_t)(b * NT + j)) * NDIN]
        : (const float4*)&queries[((size_t)(b * NG + (j - NT))) * NDIN];
    float4 v = src[dq];
    short4 o;
    o.x = f2bfs(v.x); o.y = f2bfs(v.y); o.z = f2bfs(v.z); o.w = f2bfs(v.w);
    *(short4*)((short*)X + ((size_t)(b * NS + p)) * NDIN + dq * 4) = o;
}

// ---------------- W1 GEMM: 128x128 tile, 2-phase BK=32 dbuf prefetch, gelu, bf16 out -----------
__global__ __launch_bounds__(256) void bgemmw1_k(const __hip_bfloat16* __restrict__ A,
        const __hip_bfloat16* __restrict__ Bt, __hip_bfloat16* __restrict__ Cout,
        const float* __restrict__ bias, int M, int N, int K)
{
    __shared__ __align__(16) short SM[4][128 * 32];   // A0/A1/B0/B1 (BK=32 dbuf); epilogue reuse
    const int tid = threadIdx.x;
    const int wave = tid >> 6, lane = tid & 63;
    const int quad = lane >> 4, l16 = lane & 15;
    const int wm = wave >> 1, wn = wave & 1;
    int bx = blockIdx.x, by = blockIdx.y;
    swzxy(bx, by, gridDim.x, gridDim.y);
    const size_t bm = (size_t)by * 128, bn = (size_t)bx * 128;
    const int sw = (l16 >> 1) & 3;
    const short* Ag = (const short*)A;
    const short* Bg = (const short*)Bt;
    const int lrow = lane >> 2;
    const int lchunk = (lane & 3) ^ ((lane >> 3) & 3);
    const int rS = wave * 32;

    floatx4 acc[4][4];
#pragma unroll
    for (int i = 0; i < 4; ++i)
#pragma unroll
        for (int j = 0; j < 4; ++j) acc[i][j] = (floatx4){0.f, 0.f, 0.f, 0.f};

    {   // prologue: stage k0=0 into buffer 0
        const size_t ra = (bm + rS + lrow) * (size_t)K + lchunk * 8;
        const size_t rb = (bn + rS + lrow) * (size_t)K + lchunk * 8;
        gload_lds16(Ag + ra,                    &SM[0][rS * 32]);
        gload_lds16(Ag + ra + 16 * (size_t)K,   &SM[0][(rS + 16) * 32]);
        gload_lds16(Bg + rb,                    &SM[2][rS * 32]);
        gload_lds16(Bg + rb + 16 * (size_t)K,   &SM[2][(rS + 16) * 32]);
    }
    __syncthreads();
    int cur = 0;
    for (int k0 = 0; k0 < K; k0 += 32) {
        if (k0 + 32 < K) {
            const int nx = cur ^ 1;
            const size_t ra = (bm + rS + lrow) * (size_t)K + (k0 + 32) + lchunk * 8;
            const size_t rb = (bn + rS + lrow) * (size_t)K + (k0 + 32) + lchunk * 8;
            gload_lds16(Ag + ra,                  &SM[nx][rS * 32]);
            gload_lds16(Ag + ra + 16 * (size_t)K, &SM[nx][(rS + 16) * 32]);
            gload_lds16(Bg + rb,                  &SM[2 + nx][rS * 32]);
            gload_lds16(Bg + rb + 16 * (size_t)K, &SM[2 + nx][(rS + 16) * 32]);
        }
        shortx8 af[4], bf[4];
#pragma unroll
        for (int t = 0; t < 4; ++t) {
            af[t] = *(const shortx8*)&SM[cur][(wm * 64 + t * 16 + l16) * 32 + ((quad ^ sw) * 8)];
            bf[t] = *(const shortx8*)&SM[2 + cur][(wn * 64 + t * 16 + l16) * 32 + ((quad ^ sw) * 8)];
        }
#pragma unroll
        for (int mt = 0; mt < 4; ++mt)
#pragma unroll
            for (int nt = 0; nt < 4; ++nt)
                acc[mt][nt] = __builtin_amdgcn_mfma_f32_16x16x32_bf16(af[mt], bf[nt], acc[mt][nt], 0, 0, 0);
        __syncthreads();
        cur ^= 1;
    }
    // LDS-staged coalesced epilogue (per-wave region, intra-wave only); loop ended with barrier
    const size_t mbase = bm + wm * 64;
    const size_t nbase = bn + wn * 64;
    short* ep = &SM[wave][0];   // 4096 shorts = 64x64
#pragma unroll
    for (int nt = 0; nt < 4; ++nt) {
        const size_t n = nbase + nt * 16 + l16;
        const float bz = bias[n];
        const int col = nt * 16 + l16;
#pragma unroll
        for (int mt = 0; mt < 4; ++mt)
#pragma unroll
            for (int r = 0; r < 4; ++r) {
                const int rl = mt * 16 + quad * 4 + r;
                float e = gelu_f(acc[mt][nt][r] + bz);
                ep[rl * 64 + (((col >> 3) ^ (rl & 7)) * 8) + (col & 7)] = f2bfs(e);
            }
    }
    __asm__ __volatile__("" ::: "memory");
#pragma unroll
    for (int c2 = 0; c2 < 8; ++c2) {
        const int rl = c2 * 8 + (lane >> 3);
        const int cc = lane & 7;
        shortx8 v = *(const shortx8*)&ep[rl * 64 + ((cc ^ (rl & 7)) * 8)];
        *(shortx8*)((short*)Cout + (mbase + rl) * N + nbase + cc * 8) = v;
    }
}

// ---------------- QKV GEMM: fused RoPE + head-major + V-transpose, 2-phase BK=32 dbuf ----------
__global__ __launch_bounds__(256) void bgemmqkv_k(const __hip_bfloat16* __restrict__ A,
        const __hip_bfloat16* __restrict__ Bt, __hip_bfloat16* __restrict__ qh,
        __hip_bfloat16* __restrict__ kh, __hip_bfloat16* __restrict__ vT,
        const float2* __restrict__ tab)
{
    __shared__ __align__(16) short SM[4][128 * 32];
    const int tid = threadIdx.x;
    const int wave = tid >> 6, lane = tid & 63;
    const int quad = lane >> 4, l16 = lane & 15;
    const int wm = wave >> 1, wn = wave & 1;
    int bx = blockIdx.x, by = blockIdx.y;
    swzxy(bx, by, gridDim.x, gridDim.y);
    const size_t bm = (size_t)by * 128, bn = (size_t)bx * 128;
    const int sw = (l16 >> 1) & 3;
    const int K = 512;
    const short* Ag = (const short*)A;
    const short* Bg = (const short*)Bt;
    const int lrow = lane >> 2;
    const int lchunk = (lane & 3) ^ ((lane >> 3) & 3);
    const int rS = wave * 32;

    floatx4 acc[4][4];
#pragma unroll
    for (int i = 0; i < 4; ++i)
#pragma unroll
        for (int j = 0; j < 4; ++j) acc[i][j] = (floatx4){0.f, 0.f, 0.f, 0.f};

    {   // prologue
        const size_t ra = (bm + rS + lrow) * (size_t)K + lchunk * 8;
        const size_t rb = (bn + rS + lrow) * (size_t)K + lchunk * 8;
        gload_lds16(Ag + ra,                  &SM[0][rS * 32]);
        gload_lds16(Ag + ra + 16 * (size_t)K, &SM[0][(rS + 16) * 32]);
        gload_lds16(Bg + rb,                  &SM[2][rS * 32]);
        gload_lds16(Bg + rb + 16 * (size_t)K, &SM[2][(rS + 16) * 32]);
    }
    __syncthreads();
    int cur = 0;
    for (int k0 = 0; k0 < K; k0 += 32) {
        if (k0 + 32 < K) {
            const int nx = cur ^ 1;
            const size_t ra = (bm + rS + lrow) * (size_t)K + (k0 + 32) + lchunk * 8;
            const size_t rb = (bn + rS + lrow) * (size_t)K + (k0 + 32) + lchunk * 8;
            gload_lds16(Ag + ra,                  &SM[nx][rS * 32]);
            gload_lds16(Ag + ra + 16 * (size_t)K, &SM[nx][(rS + 16) * 32]);
            gload_lds16(Bg + rb,                  &SM[2 + nx][rS * 32]);
            gload_lds16(Bg + rb + 16 * (size_t)K, &SM[2 + nx][(rS + 16) * 32]);
        }
        shortx8 af[4], bf[4];
#pragma unroll
        for (int t = 0; t < 4; ++t) {
            af[t] = *(const shortx8*)&SM[cur][(wm * 64 + t * 16 + l16) * 32 + ((quad ^ sw) * 8)];
            bf[t] = *(const shortx8*)&SM[2 + cur][(wn * 64 + t * 16 + l16) * 32 + ((quad ^ sw) * 8)];
        }
#pragma unroll
        for (int mt = 0; mt < 4; ++mt)
#pragma unroll
            for (int nt = 0; nt < 4; ++nt)
                acc[mt][nt] = __builtin_amdgcn_mfma_f32_16x16x32_bf16(af[mt], bf[nt], acc[mt][nt], 0, 0, 0);
        __syncthreads();
        cur ^= 1;
    }
    short* ep = &SM[wave][0];
    const int bidx = (int)(bm / NS);
    const int sbase = (int)(bm - (size_t)bidx * NS) + wm * 64;
    const int region = (int)(bn >> 9);     // 0=q, 1=k, 2=v
    if (region < 2) {
        const float qsc = region ? 1.0f : 0.18033688011112043f;  // 0.125 * log2(e)
        const int h = (int)((((int)bn & 511) + wn * 64) >> 6);
        // stage rotated values as [s_local 64][d 64]
#pragma unroll
        for (int nt = 0; nt < 2; ++nt) {
            const int d1 = nt * 16 + l16, d2 = d1 + 32;
            const float2* tp = tab + d1;
#pragma unroll
            for (int mt = 0; mt < 4; ++mt)
#pragma unroll
                for (int r = 0; r < 4; ++r) {
                    const int sl = mt * 16 + quad * 4 + r;
                    const int s = sbase + sl;
                    float x1 = acc[mt][nt][r], x2 = acc[mt][nt + 2][r];
                    float2 cs = tp[s * 32];
                    ep[sl * 64 + (((d1 >> 3) ^ (sl & 7)) * 8) + (d1 & 7)] = f2bfs(qsc * (x1 * cs.x - x2 * cs.y));
                    ep[sl * 64 + (((d2 >> 3) ^ (sl & 7)) * 8) + (d2 & 7)] = f2bfs(qsc * (x1 * cs.y + x2 * cs.x));
                }
        }
        __asm__ __volatile__("" ::: "memory");
        short* dst = (short*)(region ? kh : qh) + ((size_t)(bidx * NH + h)) * NS * NDH;
#pragma unroll
        for (int c2 = 0; c2 < 8; ++c2) {
            const int sl = c2 * 8 + (lane >> 3);
            const int cc = lane & 7;
            shortx8 v = *(const shortx8*)&ep[sl * 64 + ((cc ^ (sl & 7)) * 8)];
            *(shortx8*)(dst + (size_t)(sbase + sl) * NDH + cc * 8) = v;
        }
    } else {
        const int base = (int)(bn - 1024) + wn * 64;
        const int h = base >> 6;
        // stage transposed [d_local 64][s_local 64]
#pragma unroll
        for (int nt = 0; nt < 4; ++nt) {
            const int dl = nt * 16 + l16;
#pragma unroll
            for (int mt = 0; mt < 4; ++mt)
#pragma unroll
                for (int r = 0; r < 4; ++r) {
                    const int sl = mt * 16 + quad * 4 + r;
                    ep[dl * 64 + (((sl >> 3) ^ (dl & 7)) * 8) + (sl & 7)] = f2bfs(acc[mt][nt][r]);
                }
        }
        __asm__ __volatile__("" ::: "memory");
        short* vp = (short*)vT + ((size_t)(bidx * NH + h)) * NDH * NS;
#pragma unroll
        for (int c2 = 0; c2 < 8; ++c2) {
            const int dl = c2 * 8 + (lane >> 3);
            const int cc = lane & 7;
            shortx8 v = *(const shortx8*)&ep[dl * 64 + ((cc ^ (dl & 7)) * 8)];
            *(shortx8*)(vp + (size_t)dl * NS + sbase + cc * 8) = v;
        }
    }
}

// ---------------- bf16 MFMA GEMM 64x128 tile, 2-phase BK=32 dbuf (N=512 shapes) ----------------
// EPI 0: acc+bias?  EPI 2: res + ls*(acc+bias?)  EPI 4: masked transposed writeout (W_out)
template <int EPI>
__global__ __launch_bounds__(256) void bgemm64_k(const __hip_bfloat16* __restrict__ A,
        const __hip_bfloat16* __restrict__ Bt, void* __restrict__ Cout,
        const float* __restrict__ bias, const float* __restrict__ ls,
        const float* __restrict__ res, const int* __restrict__ nsegp, int M, int N, int K)
{
    __shared__ __align__(16) short As[2][64 * 32];    //  8 KB
    __shared__ __align__(16) short Bs[2][128 * 32];   // 16 KB
    const int tid = threadIdx.x;
    const int wave = tid >> 6, lane = tid & 63;
    const int quad = lane >> 4, l16 = lane & 15;
    const int wm = wave >> 1, wn = wave & 1;
    int bx = blockIdx.x, by = blockIdx.y;
    swzxy(bx, by, gridDim.x, gridDim.y);
    const size_t bm = (size_t)by * 64, bn = (size_t)bx * 128;
    const int sw = (l16 >> 1) & 3;
    const short* Ag = (const short*)A;
    const short* Bg = (const short*)Bt;
    const int lrow = lane >> 2;
    const int lchunk = (lane & 3) ^ ((lane >> 3) & 3);
    const int rA = wave * 16, rB = wave * 32;

    floatx4 acc[2][4];
#pragma unroll
    for (int i = 0; i < 2; ++i)
#pragma unroll
        for (int j = 0; j < 4; ++j) acc[i][j] = (floatx4){0.f, 0.f, 0.f, 0.f};

    {   // prologue: stage k0=0 into buffer 0
        const size_t ra = (bm + rA + lrow) * (size_t)K + lchunk * 8;
        const size_t rb = (bn + rB + lrow) * (size_t)K + lchunk * 8;
        gload_lds16(Ag + ra,                  &As[0][rA * 32]);
        gload_lds16(Bg + rb,                  &Bs[0][rB * 32]);
        gload_lds16(Bg + rb + 16 * (size_t)K, &Bs[0][(rB + 16) * 32]);
    }
    __syncthreads();
    int cur = 0;
    for (int k0 = 0; k0 < K; k0 += 32) {
        if (k0 + 32 < K) {
            const int nx = cur ^ 1;
            const size_t ra = (bm + rA + lrow) * (size_t)K + (k0 + 32) + lchunk * 8;
            const size_t rb = (bn + rB + lrow) * (size_t)K + (k0 + 32) + lchunk * 8;
            gload_lds16(Ag + ra,                  &As[nx][rA * 32]);
            gload_lds16(Bg + rb,                  &Bs[nx][rB * 32]);
            gload_lds16(Bg + rb + 16 * (size_t)K, &Bs[nx][(rB + 16) * 32]);
        }
        shortx8 af[2], bf[4];
#pragma unroll
        for (int t = 0; t < 2; ++t)
            af[t] = *(const shortx8*)&As[cur][(wm * 32 + t * 16 + l16) * 32 + ((quad ^ sw) * 8)];
#pragma unroll
        for (int t = 0; t < 4; ++t)
            bf[t] = *(const shortx8*)&Bs[cur][(wn * 64 + t * 16 + l16) * 32 + ((quad ^ sw) * 8)];
#pragma unroll
        for (int mt = 0; mt < 2; ++mt)
#pragma unroll
            for (int nt = 0; nt < 4; ++nt)
                acc[mt][nt] = __builtin_amdgcn_mfma_f32_16x16x32_bf16(af[mt], bf[nt], acc[mt][nt], 0, 0, 0);
        __syncthreads();
        cur ^= 1;
    }
    const size_t mbase = bm + wm * 32;
    const size_t nbase = bn + wn * 64;
#pragma unroll
    for (int nt = 0; nt < 4; ++nt) {
        const size_t n = nbase + nt * 16 + l16;
        const float bz = bias ? bias[n] : 0.f;
        const float lz = (EPI == 2) ? ls[n] : 0.f;
#pragma unroll
        for (int mt = 0; mt < 2; ++mt) {
#pragma unroll
            for (int r = 0; r < 4; ++r) {
                const size_t m = mbase + mt * 16 + quad * 4 + r;
                float e = acc[mt][nt][r] + bz;
                if (EPI == 4) {
                    const int b = (int)(m >> 7), g = (int)(m & 127);
                    float val = (g < nsegp[b]) ? e : 0.0f;
                    ((float*)Cout)[(size_t)b * (NDIN * NG) + n * NG + g] = val;
                } else {
                    const size_t off = m * N + n;
                    if (EPI == 2) e = res[off] + lz * e;
                    ((float*)Cout)[off] = e;
                }
            }
        }
    }
}

// ---------------- wave-per-row LayerNorm, 4 rows/block (fp32 in -> bf16 out) ----------------
__global__ __launch_bounds__(256) void lnw_k(const float* __restrict__ in,
        __hip_bfloat16* __restrict__ out, const float* __restrict__ gam, const float* __restrict__ bet)
{
    const int r = blockIdx.x * 4 + (threadIdx.x >> 6);
    const int t = threadIdx.x & 63;
    const float4* xp = (const float4*)(in + (size_t)r * NDM);
    float4 a = xp[t * 2], b4 = xp[t * 2 + 1];
    float s = a.x + a.y + a.z + a.w + b4.x + b4.y + b4.z + b4.w;
#pragma unroll
    for (int o = 1; o < 64; o <<= 1) s += __shfl_xor(s, o);
    const float mean = s * (1.0f / NDM);
    float dx[8] = {a.x - mean, a.y - mean, a.z - mean, a.w - mean,
                   b4.x - mean, b4.y - mean, b4.z - mean, b4.w - mean};
    float v = 0.f;
#pragma unroll
    for (int i = 0; i < 8; ++i) v += dx[i] * dx[i];
#pragma unroll
    for (int o = 1; o < 64; o <<= 1) v += __shfl_xor(v, o);
    const float inv = rsqrtf(v * (1.0f / NDM) + 1e-5f);
    const float4* gp = (const float4*)gam;
    const float4* bp = (const float4*)bet;
    float4 g0 = gp[t * 2], g1 = gp[t * 2 + 1], q0 = bp[t * 2], q1 = bp[t * 2 + 1];
    shortx8 o8;
    o8[0] = f2bfs(dx[0] * inv * g0.x + q0.x);
    o8[1] = f2bfs(dx[1] * inv * g0.y + q0.y);
    o8[2] = f2bfs(dx[2] * inv * g0.z + q0.z);
    o8[3] = f2bfs(dx[3] * inv * g0.w + q0.w);
    o8[4] = f2bfs(dx[4] * inv * g1.x + q1.x);
    o8[5] = f2bfs(dx[5] * inv * g1.y + q1.y);
    o8[6] = f2bfs(dx[6] * inv * g1.z + q1.z);
    o8[7] = f2bfs(dx[7] * inv * g1.w + q1.w);
    *(shortx8*)((short*)out + (size_t)r * NDM + t * 8) = o8;
}

// ---------------- wave-per-row final LN over gathered query rows ----------------
__global__ __launch_bounds__(64) void lnwg_k(const float* __restrict__ h,
        __hip_bfloat16* __restrict__ out, const float* __restrict__ gam, const float* __restrict__ bet,
        const int* __restrict__ qpos)
{
    const int r = blockIdx.x, t = threadIdx.x;   // r = b*NG + g
    const int b = r >> 7;
    const int src = qpos[r];
    const float4* xp = (const float4*)(h + ((size_t)(b * NS + src)) * NDM);
    float4 a = xp[t * 2], b4 = xp[t * 2 + 1];
    float s = a.x + a.y + a.z + a.w + b4.x + b4.y + b4.z + b4.w;
#pragma unroll
    for (int o = 1; o < 64; o <<= 1) s += __shfl_xor(s, o);
    const float mean = s * (1.0f / NDM);
    float dx[8] = {a.x - mean, a.y - mean, a.z - mean, a.w - mean,
                   b4.x - mean, b4.y - mean, b4.z - mean, b4.w - mean};
    float v = 0.f;
#pragma unroll
    for (int i = 0; i < 8; ++i) v += dx[i] * dx[i];
#pragma unroll
    for (int o = 1; o < 64; o <<= 1) v += __shfl_xor(v, o);
    const float inv = rsqrtf(v * (1.0f / NDM) + 1e-5f);
    const float4* gp = (const float4*)gam;
    const float4* bp = (const float4*)bet;
    float4 g0 = gp[t * 2], g1 = gp[t * 2 + 1], q0 = bp[t * 2], q1 = bp[t * 2 + 1];
    shortx8 o8;
    o8[0] = f2bfs(dx[0] * inv * g0.x + q0.x);
    o8[1] = f2bfs(dx[1] * inv * g0.y + q0.y);
    o8[2] = f2bfs(dx[2] * inv * g0.z + q0.z);
    o8[3] = f2bfs(dx[3] * inv * g0.w + q0.w);
    o8[4] = f2bfs(dx[4] * inv * g1.x + q1.x);
    o8[5] = f2bfs(dx[5] * inv * g1.y + q1.y);
    o8[6] = f2bfs(dx[6] * inv * g1.z + q1.z);
    o8[7] = f2bfs(dx[7] * inv * g1.w + q1.w);
    *(shortx8*)((short*)out + (size_t)r * NDM + t * 8) = o8;
}

// ---------------- flash attention v13: 32 q-rows/wave — K/V fragment reads shared 2x ----------
// R8 model: the wall is LDS THROUGHPUT (per CU ~85K cycles of ds ops ~ 35µs of the 54µs),
// dominated by the 8 K-frag + 8 V-frag b128 reads per wave-tile. v13 keeps the exact v8
// dataflow but each wave owns TWO 16-q-row chunks: K/V fragments are read ONCE per tile and
// feed both chunks' MFMAs -> per-q-row LDS reads drop ~45% (18 -> 20 b128 per 2x work).
// Block = 256 thr (4 waves x 32 q = 128 q-rows); staging pattern identical to v8; Pl = 128
// rows. LDS 34.8KB. Grid 576 (2.25 blk/CU). Numerics: op-for-op identical to v8/v12.
#define FKT 64
#define FKP 68
#define NTL (NS / FKT)   // 18
#define QB  128
__global__ __launch_bounds__(256) void fattn_k(const __hip_bfloat16* __restrict__ qb,
        const __hip_bfloat16* __restrict__ kb, const __hip_bfloat16* __restrict__ vbT,
        __hip_bfloat16* __restrict__ o)
{
    __shared__ __align__(16) short Ks[FKT * FKP];   //  8704 B
    __shared__ __align__(16) short Vt[NDH * FKP];   //  8704 B
    __shared__ __align__(16) short Pl[QB * FKP];    // 17408 B
    const int tid = threadIdx.x;
    const int wave = tid >> 6, lane = tid & 63;
    const int quad = lane >> 4, l16 = lane & 15;
    const int L = blockIdx.x;                 // 576 = 8 xcd * 8 bh-low * 9 qblk
    const int xcd = L & 7, sl = L >> 3;       // sl in 0..71
    const int bh = (xcd << 3) | (sl & 7);
    const int q0 = (sl >> 3) * QB;            // 0..8 * 128
    const int bb = bh >> 3, hh = bh & 7;
    const short* qbase = (const short*)qb + (size_t)bh * NS * NDH;
    const short* kbase = (const short*)kb + (size_t)bh * NS * NDH;
    const short* vbase = (const short*)vbT + (size_t)bh * NDH * NS;

    // Q fragments for the wave's two 16-row chunks
    shortx8 Qa0, Qa1, Qb0, Qb1;
    {
        const short* qp = qbase + (size_t)(q0 + wave * 32 + l16) * NDH + quad * 8;
        Qa0 = *(const shortx8*)qp;
        Qa1 = *(const shortx8*)(qp + 32);
        const short* qp2 = qp + 16 * NDH;
        Qb0 = *(const shortx8*)qp2;
        Qb1 = *(const shortx8*)(qp2 + 32);
    }
    shortx8 Of;                       // all-ones bf16 B-fragment for the denominator MFMA
#pragma unroll
    for (int i = 0; i < 8; ++i) Of[i] = 0x3F80;

    floatx4 OaccA[4], OaccB[4];
#pragma unroll
    for (int i = 0; i < 4; ++i) {
        OaccA[i] = (floatx4){0.f, 0.f, 0.f, 0.f};
        OaccB[i] = (floatx4){0.f, 0.f, 0.f, 0.f};
    }
    floatx4 O5a = (floatx4){0.f, 0.f, 0.f, 0.f};
    floatx4 O5b = (floatx4){0.f, 0.f, 0.f, 0.f};

    const int sr = tid >> 2, sc = (tid & 3) * 16;    // v8 staging: 256 thr cover 64x64, 2x16B each
    const int prowA = wave * 32 + l16;               // wave-private P rows (chunk A)
    const int prowB = prowA + 16;                    // chunk B
    const short* kg = kbase + (size_t)sr * NDH + sc;
    const short* vg = vbase + (size_t)sr * NS + sc;
    shortx8 pk0 = *(const shortx8*)kg, pk1 = *(const shortx8*)(kg + 8);
    shortx8 pv0 = *(const shortx8*)vg, pv1 = *(const shortx8*)(vg + 8);

    for (int t = 0; t < NTL; ++t) {
        __syncthreads();
        *(shortx8*)&Ks[sr * FKP + sc]     = pk0;
        *(shortx8*)&Ks[sr * FKP + sc + 8] = pk1;
        *(shortx8*)&Vt[sr * FKP + sc]     = pv0;
        *(shortx8*)&Vt[sr * FKP + sc + 8] = pv1;
        __syncthreads();
        if (t + 1 < NTL) {
            kg += FKT * NDH; vg += FKT;
            pk0 = *(const shortx8*)kg; pk1 = *(const shortx8*)(kg + 8);
            pv0 = *(const shortx8*)vg; pv1 = *(const shortx8*)(vg + 8);
        }

        // K fragments read ONCE, feed both chunks (S^T = K Q^T; Q pre-scaled -> exp2 domain)
        floatx4 Sa[4], Sb[4];
#pragma unroll
        for (int kbk = 0; kbk < 4; ++kbk) {
            shortx8 kf0 = *(const shortx8*)&Ks[(kbk * 16 + l16) * FKP + quad * 8];
            shortx8 kf1 = *(const shortx8*)&Ks[(kbk * 16 + l16) * FKP + 32 + quad * 8];
            floatx4 sa = (floatx4){0.f, 0.f, 0.f, 0.f};
            sa = __builtin_amdgcn_mfma_f32_16x16x32_bf16(kf0, Qa0, sa, 0, 0, 0);
            sa = __builtin_amdgcn_mfma_f32_16x16x32_bf16(kf1, Qa1, sa, 0, 0, 0);
            Sa[kbk] = sa;
            floatx4 sb = (floatx4){0.f, 0.f, 0.f, 0.f};
            sb = __builtin_amdgcn_mfma_f32_16x16x32_bf16(kf0, Qb0, sb, 0, 0, 0);
            sb = __builtin_amdgcn_mfma_f32_16x16x32_bf16(kf1, Qb1, sb, 0, 0, 0);
            Sb[kbk] = sb;
        }
        // no-max softmax numerators for both chunks; RTZ pack (bias cancels in num/denom)
#pragma unroll
        for (int kbk = 0; kbk < 4; ++kbk) {
            uint2 ua, ub;
            ua.x = pack_bf2_rz(exp2f(Sa[kbk][0]), exp2f(Sa[kbk][1]));
            ua.y = pack_bf2_rz(exp2f(Sa[kbk][2]), exp2f(Sa[kbk][3]));
            *(uint2*)&Pl[prowA * FKP + kbk * 16 + quad * 4] = ua;
            ub.x = pack_bf2_rz(exp2f(Sb[kbk][0]), exp2f(Sb[kbk][1]));
            ub.y = pack_bf2_rz(exp2f(Sb[kbk][2]), exp2f(Sb[kbk][3]));
            *(uint2*)&Pl[prowB * FKP + kbk * 16 + quad * 4] = ub;
        }
        __asm__ __volatile__("" ::: "memory");   // P rows are wave-private: no barrier needed
        shortx8 Pa0 = *(const shortx8*)&Pl[prowA * FKP + quad * 8];
        shortx8 Pa1 = *(const shortx8*)&Pl[prowA * FKP + 32 + quad * 8];
        shortx8 Pb0 = *(const shortx8*)&Pl[prowB * FKP + quad * 8];
        shortx8 Pb1 = *(const shortx8*)&Pl[prowB * FKP + 32 + quad * 8];
        __builtin_amdgcn_s_setprio(1);
        // V fragments read ONCE, feed both chunks
#pragma unroll
        for (int ct = 0; ct < 4; ++ct) {
            shortx8 vf0 = *(const shortx8*)&Vt[(ct * 16 + l16) * FKP + quad * 8];
            shortx8 vf1 = *(const shortx8*)&Vt[(ct * 16 + l16) * FKP + 32 + quad * 8];
            OaccA[ct] = __builtin_amdgcn_mfma_f32_16x16x32_bf16(Pa0, vf0, OaccA[ct], 0, 0, 0);
            OaccA[ct] = __builtin_amdgcn_mfma_f32_16x16x32_bf16(Pa1, vf1, OaccA[ct], 0, 0, 0);
            OaccB[ct] = __builtin_amdgcn_mfma_f32_16x16x32_bf16(Pb0, vf0, OaccB[ct], 0, 0, 0);
            OaccB[ct] = __builtin_amdgcn_mfma_f32_16x16x32_bf16(Pb1, vf1, OaccB[ct], 0, 0, 0);
        }
        O5a = __builtin_amdgcn_mfma_f32_16x16x32_bf16(Pa0, Of, O5a, 0, 0, 0);
        O5a = __builtin_amdgcn_mfma_f32_16x16x32_bf16(Pa1, Of, O5a, 0, 0, 0);
        O5b = __builtin_amdgcn_mfma_f32_16x16x32_bf16(Pb0, Of, O5b, 0, 0, 0);
        O5b = __builtin_amdgcn_mfma_f32_16x16x32_bf16(Pb1, Of, O5b, 0, 0, 0);
        __builtin_amdgcn_s_setprio(0);
    }
#pragma unroll
    for (int i = 0; i < 4; ++i) {
        // O5 columns are all equal (B = ones): lane's own value IS its row's denominator
        const float invA = 1.0f / O5a[i];
        const float invB = 1.0f / O5b[i];
        const int rowA = q0 + wave * 32 + quad * 4 + i;
        __hip_bfloat16* opA = o + ((size_t)(bb * NS + rowA)) * NDM + hh * NDH + l16;
        opA[0]  = __float2bfloat16(OaccA[0][i] * invA);
        opA[16] = __float2bfloat16(OaccA[1][i] * invA);
        opA[32] = __float2bfloat16(OaccA[2][i] * invA);
        opA[48] = __float2bfloat16(OaccA[3][i] * invA);
        __hip_bfloat16* opB = opA + (size_t)16 * NDM;
        opB[0]  = __float2bfloat16(OaccB[0][i] * invB);
        opB[16] = __float2bfloat16(OaccB[1][i] * invB);
        opB[32] = __float2bfloat16(OaccB[2][i] * invB);
        opB[48] = __float2bfloat16(OaccB[3][i] * invB);
    }
}

extern "C" void kernel_launch(void* const* d_in, const int* in_sizes, int n_in,
                              void* d_out, int out_size, void* d_ws, size_t ws_size,
                              hipStream_t stream) {
    const float* features = (const float*)d_in[0];
    const float* align    = (const float*)d_in[1];
    const int*   nseg     = (const int*)d_in[2];
    const float* W_in  = (const float*)d_in[3];
    const float* b_in  = (const float*)d_in[4];
    const float* ln1_s = (const float*)d_in[5];
    const float* ln1_b = (const float*)d_in[6];
    const float* Wq = (const float*)d_in[7];
    const float* Wk = (const float*)d_in[8];
    const float* Wv = (const float*)d_in[9];
    const float* Wo = (const float*)d_in[10];
    const float* ls1   = (const float*)d_in[11];
    const float* ln2_s = (const float*)d_in[12];
    const float* ln2_b = (const float*)d_in[13];
    const float* W1 = (const float*)d_in[14];
    const float* b1 = (const float*)d_in[15];
    const float* W2 = (const float*)d_in[16];
    const float* b2 = (const float*)d_in[17];
    const float* ls2   = (const float*)d_in[18];
    const float* lnf_s = (const float*)d_in[19];
    const float* lnf_b = (const float*)d_in[20];
    const float* W_out = (const float*)d_in[21];
    const float* b_out = (const float*)d_in[22];

    const size_t SZ_BSD = (size_t)NB * NS * NDM;      // 4,718,592

    // ---- workspace map: weights & index arrays FIRST, then activations ----
    float* p = (float*)d_ws;
    __hip_bfloat16* w_inT  = (__hip_bfloat16*)p;
    __hip_bfloat16* wqkvT0 = w_inT + 512 * 512;
    __hip_bfloat16* wqkvT1 = wqkvT0 + 1536 * 512;
    __hip_bfloat16* woT0   = wqkvT1 + 1536 * 512;
    __hip_bfloat16* woT1   = woT0 + 512 * 512;
    __hip_bfloat16* w1T0   = woT1 + 512 * 512;
    __hip_bfloat16* w1T1   = w1T0 + 2048 * 512;
    __hip_bfloat16* w2T0   = w1T1 + 2048 * 512;
    __hip_bfloat16* w2T1   = w2T0 + 512 * 2048;
    __hip_bfloat16* woutT  = w2T1 + 512 * 2048;
    int* glast = (int*)(woutT + 512 * 512);
    int* perm  = glast + NB * NG;
    int* qpos  = perm + NB * NS;
    float2* ropetab = (float2*)(qpos + NB * NG);       // 36864 float2
    p = (float*)(ropetab + NS * 32);

    float* featT = p; p += (size_t)NB * NT * NDIN;                      // fp32 [b][t][d]
    float* hbuf = p; p += SZ_BSD;                                       // fp32 residual
    __hip_bfloat16* ybuf = (__hip_bfloat16*)p;  p += SZ_BSD / 2;        // bf16 LN out
    __hip_bfloat16* obuf = (__hip_bfloat16*)p;  p += SZ_BSD / 2;        // bf16 attn out
    __hip_bfloat16* ubuf = (__hip_bfloat16*)p;  p += SZ_BSD * 2;        // bf16 [9216][2048]; also qh+kh
    __hip_bfloat16* xin  = (__hip_bfloat16*)p;  p += SZ_BSD / 2;        // bf16 X; also vT
    float* quer = p; p += (size_t)NB * NG * NDIN;
    __hip_bfloat16* hq = (__hip_bfloat16*)p; p += (size_t)NB * NG * NDM / 2;
    const size_t needed = (size_t)((char*)p - (char*)d_ws);
    if (ws_size < needed) return;

    __hip_bfloat16* qh = ubuf;
    __hip_bfloat16* kh = ubuf + SZ_BSD;
    __hip_bfloat16* vT = xin;

    // ---- prep (merged: ropetab + ftrans + weight transposes in one dispatch) ----
    prep0_k<<<144 + 4096 + 6656, 256, 0, stream>>>(ropetab, features, featT,
            W_in, Wq, Wk, Wv, Wo, W1, W2, W_out,
            w_inT, wqkvT0, wqkvT1, woT0, woT1, w1T0, w1T1, w2T0, w2T1, woutT);
    pool_k<<<NB * NG, 256, 0, stream>>>(align, featT, glast, quer);
    rank_k<<<dim3((NS + 255) / 256, NB), 256, 0, stream>>>(glast, nseg, perm, qpos);
    buildx_k<<<(NB * NS * (NDIN / 4) + 255) / 256, 256, 0, stream>>>(featT, quer, perm, xin);

    const int M = NB * NS;   // 9216
    bgemm64_k<0><<<dim3(NDM / 128, M / 64), 256, 0, stream>>>(xin, w_inT, hbuf, b_in, nullptr, nullptr, nullptr, M, NDM, NDIN);

    for (int l = 0; l < NL; ++l) {
        __hip_bfloat16* wqkvT = (l ? wqkvT1 : wqkvT0);
        __hip_bfloat16* woT   = (l ? woT1 : woT0);
        __hip_bfloat16* w1T   = (l ? w1T1 : w1T0);
        __hip_bfloat16* w2T   = (l ? w2T1 : w2T0);

        lnw_k<<<M / 4, 256, 0, stream>>>(hbuf, ybuf, ln1_s + l * NDM, ln1_b + l * NDM);
        bgemmqkv_k<<<dim3(1536 / 128, M / 128), 256, 0, stream>>>(ybuf, wqkvT, qh, kh, vT, ropetab);
        fattn_k<<<(NS / QB) * NH * NB, 256, 0, stream>>>(qh, kh, vT, obuf);
        bgemm64_k<2><<<dim3(NDM / 128, M / 64), 256, 0, stream>>>(obuf, woT, hbuf, nullptr, ls1 + l * NDM, hbuf, nullptr, M, NDM, NDM);
        lnw_k<<<M / 4, 256, 0, stream>>>(hbuf, ybuf, ln2_s + l * NDM, ln2_b + l * NDM);
        bgemmw1_k<<<dim3(NFF / 128, M / 128), 256, 0, stream>>>(ybuf, w1T, ubuf, b1 + l * NFF, M, NFF, NDM);
        bgemm64_k<2><<<dim3(NDM / 128, M / 64), 256, 0, stream>>>(ubuf, w2T, hbuf, b2 + l * NDM, ls2 + l * NDM, hbuf, nullptr, M, NDM, NFF);
    }

    lnwg_k<<<NB * NG, 64, 0, stream>>>(hbuf, hq, lnf_s, lnf_b, qpos);
    bgemm64_k<4><<<dim3(NDIN / 128, (NB * NG) / 64), 256, 0, stream>>>(hq, woutT, d_out, b_out, nullptr, nullptr, nseg, NB * NG, NDIN, NDM);
}

// Round 10
// 596.373 us; speedup vs baseline: 1.0325x; 1.0325x over previous
//
#include <hip/hip_runtime.h>
#include <hip/hip_bf16.h>
#include <math.h>

// Problem constants
#define NB   8
#define NT   1024
#define NG   128
#define NS   1152      // NT + NG
#define NDIN 512
#define NDM  512
#define NH   8
#define NDH  64
#define NFF  2048
#define NL   2

typedef __attribute__((ext_vector_type(4))) float  floatx4;
typedef __attribute__((ext_vector_type(8))) short  shortx8;

__device__ __forceinline__ float gelu_f(float x) {
    float u = 1.5957691216057308f * (x + 0.044715f * x * x * x);
    return x / (1.0f + __expf(-u));
}

__device__ __forceinline__ void gload_lds16(const void* g, void* l) {
    __builtin_amdgcn_global_load_lds((const __attribute__((address_space(1))) unsigned int*)g,
                                     (__attribute__((address_space(3))) unsigned int*)l, 16, 0, 0);
}

__device__ __forceinline__ short f2bfs(float x) {
    __hip_bfloat16 h = __float2bfloat16(x);
    return *(short*)&h;
}
// truncating (RTZ) pack of two fp32 -> bf16x2; cheap (3 VALU ops), used only for P
__device__ __forceinline__ unsigned pack_bf2_rz(float a, float b) {
    unsigned au = *(unsigned*)&a, bu = *(unsigned*)&b;
    return (au >> 16) | (bu & 0xFFFF0000u);
}

// Bijective XCD-aware block swizzle (T1/m204).  [R5: 613->608.6 µs]
__device__ __forceinline__ void swzxy(int& bx, int& by, int gx, int gy) {
    const int nwg = gx * gy;
    int flat = by * gx + bx;
    if ((nwg & 7) == 0) flat = (flat & 7) * (nwg >> 3) + (flat >> 3);
    bx = flat % gx; by = flat / gx;
}

// ---------------- merged prep: rope table + feature transpose + all weight transposes ----------------
__device__ __forceinline__ void wtile(const float* __restrict__ src,
        __hip_bfloat16* __restrict__ dst, int K, int N, int i, int tid, short tile[32][33])
{
    const int gx = N / 32;
    const int n0 = (i % gx) * 32;
    const int k0 = (i / gx) * 32;
    {
        const int r = tid >> 3, c4 = (tid & 7) * 4;
        float4 v = *(const float4*)&src[(size_t)(k0 + r) * N + n0 + c4];
        tile[c4 + 0][r] = f2bfs(v.x);
        tile[c4 + 1][r] = f2bfs(v.y);
        tile[c4 + 2][r] = f2bfs(v.z);
        tile[c4 + 3][r] = f2bfs(v.w);
    }
    __syncthreads();
    {
        const int r = tid >> 3, c4 = (tid & 7) * 4;
        short* dp = (short*)dst + (size_t)(n0 + r) * K + k0 + c4;
        short4 v;
        v.x = tile[r][c4 + 0]; v.y = tile[r][c4 + 1];
        v.z = tile[r][c4 + 2]; v.w = tile[r][c4 + 3];
        *(short4*)dp = v;
    }
}

__global__ __launch_bounds__(256) void prep0_k(
        float2* __restrict__ tab,
        const float* __restrict__ features, float* __restrict__ featT,
        const float* W_in, const float* Wq, const float* Wk, const float* Wv,
        const float* Wo, const float* W1, const float* W2, const float* W_out,
        __hip_bfloat16* w_inT, __hip_bfloat16* wqkvT0, __hip_bfloat16* wqkvT1,
        __hip_bfloat16* woT0, __hip_bfloat16* woT1,
        __hip_bfloat16* w1T0, __hip_bfloat16* w1T1,
        __hip_bfloat16* w2T0, __hip_bfloat16* w2T1, __hip_bfloat16* woutT)
{
    __shared__ __align__(16) char smem[32 * 33 * 4];
    const int tid = threadIdx.x;
    const int blk = blockIdx.x;
    if (blk < 144) {
        // rope cos/sin table
        const int idx = blk * 256 + tid;     // < 36864 = NS*32
        const int s = idx >> 5, i = idx & 31;
        const float fr = __expf(-(float)i * 0.28782313662425576f);
        const float ang = (float)s * fr;
        tab[idx] = make_float2(cosf(ang), sinf(ang));
    } else if (blk < 144 + 4096) {
        // features [b][d][t] -> featT [b][t][d]
        float (*tile)[33] = (float(*)[33])smem;
        const int v = blk - 144;
        const int t0 = (v & 31) * 32;
        const int d0 = ((v >> 5) & 15) * 32;
        const int b  = v >> 9;
        const int r = tid >> 3, c4 = (tid & 7) * 4;
        {
            float4 w = *(const float4*)&features[((size_t)(b * NDIN + d0 + r)) * NT + t0 + c4];
            tile[c4 + 0][r] = w.x; tile[c4 + 1][r] = w.y;
            tile[c4 + 2][r] = w.z; tile[c4 + 3][r] = w.w;
        }
        __syncthreads();
        {
            float4 w;
            w.x = tile[r][c4 + 0]; w.y = tile[r][c4 + 1];
            w.z = tile[r][c4 + 2]; w.w = tile[r][c4 + 3];
            *(float4*)&featT[((size_t)(b * NT + t0 + r)) * NDIN + d0 + c4] = w;
        }
    } else {
        // weight transposes
        short (*tile)[33] = (short(*)[33])smem;
        const int i = blk - (144 + 4096);    // < 6656
        const float* src; __hip_bfloat16* dst; int K, N, ti;
        if (i < 256) { src = W_in; dst = w_inT; K = 512; N = 512; ti = i; }
        else if (i < 6400) {
            int r = i - 256;
            const int l = r / 3072; r -= l * 3072;
            const size_t o5 = (size_t)l * 262144, o2 = (size_t)l * 1048576;
            if (r < 256)       { src = Wq + o5; dst = (l ? wqkvT1 : wqkvT0);          K = 512;  N = 512;  ti = r; }
            else if (r < 512)  { src = Wk + o5; dst = (l ? wqkvT1 : wqkvT0) + 262144; K = 512;  N = 512;  ti = r - 256; }
            else if (r < 768)  { src = Wv + o5; dst = (l ? wqkvT1 : wqkvT0) + 524288; K = 512;  N = 512;  ti = r - 512; }
            else if (r < 1024) { src = Wo + o5; dst = (l ? woT1 : woT0);              K = 512;  N = 512;  ti = r - 768; }
            else if (r < 2048) { src = W1 + o2; dst = (l ? w1T1 : w1T0);              K = 512;  N = 2048; ti = r - 1024; }
            else               { src = W2 + o2; dst = (l ? w2T1 : w2T0);              K = 2048; N = 512;  ti = r - 2048; }
        }
        else { src = W_out; dst = woutT; K = 512; N = 512; ti = i - 6400; }
        wtile(src, dst, K, N, ti, tid, tile);
    }
}

// ---------------- merged group-pool: stats + mean-pooled queries (featT, coalesced) ----------------
__global__ __launch_bounds__(256) void pool_k(const float* __restrict__ align,
        const float* __restrict__ featT, int* __restrict__ glast,
        float* __restrict__ queries)
{
    __shared__ float redf[256];
    __shared__ int   redi[256];
    __shared__ float aw[NT];
    const int bg = blockIdx.x;           // b*NG + g
    const int b = bg >> 7;
    const int tid = threadIdx.x;
    const float* arow = align + (size_t)bg * NT;
    float cnt = 0.f, last = 0.f;
    int tmin = NT;
    for (int t = tid; t < NT; t += 256) {
        float a = arow[t];
        cnt += a;
        last = fmaxf(last, a * (float)t);
        if (a > 0.f) tmin = min(tmin, t);
    }
    redf[tid] = cnt; __syncthreads();
    for (int s = 128; s > 0; s >>= 1) { if (tid < s) redf[tid] += redf[tid + s]; __syncthreads(); }
    float c = redf[0]; __syncthreads();
    redf[tid] = last; __syncthreads();
    for (int s = 128; s > 0; s >>= 1) { if (tid < s) redf[tid] = fmaxf(redf[tid], redf[tid + s]); __syncthreads(); }
    float l = redf[0];
    redi[tid] = tmin; __syncthreads();
    for (int s = 128; s > 0; s >>= 1) { if (tid < s) redi[tid] = min(redi[tid], redi[tid + s]); __syncthreads(); }
    const int t0 = redi[0];
    const int t1 = (int)l;
    if (tid == 0) glast[bg] = t1;
    __syncthreads();
    for (int t = t0 + tid; t <= t1; t += 256) aw[t - t0] = arow[t];
    __syncthreads();
    const float invc = 1.0f / fmaxf(c, 1.0f);
    const float* fT = featT + (size_t)b * NT * NDIN;
    for (int d = tid; d < NDIN; d += 256) {
        float s = 0.f;
        for (int t = t0; t <= t1; ++t) s += aw[t - t0] * fT[(size_t)t * NDIN + d];
        queries[(size_t)bg * NDIN + d] = s * invc;
    }
}

// ---------------- stable-argsort rank ----------------
__global__ __launch_bounds__(256) void rank_k(const int* __restrict__ glast,
        const int* __restrict__ nsegp, int* __restrict__ perm, int* __restrict__ qpos)
{
    __shared__ int dm[NS];
    __shared__ int gl[NG];
    const int b = blockIdx.y;
    const int tid = threadIdx.x;
    const int j = blockIdx.x * 256 + tid;
    if (tid < NG) gl[tid] = glast[b * NG + tid];
    const int ns = nsegp[b];
    __syncthreads();
    for (int jj = tid; jj < NS; jj += 256) {
        int d;
        if (jj < NT) {
            int t = jj, nq = 0, flen = 0;
            for (int g = 0; g < ns; ++g) {
                flen = max(flen, gl[g] + 1);
                nq += (gl[g] < t) ? 1 : 0;
            }
            d = (t < flen) ? (t + nq) : NS;
        } else {
            int g = jj - NT;
            d = (g < ns) ? (gl[g] + g + 1) : NS;
        }
        dm[jj] = d;
    }
    __syncthreads();
    if (j < NS) {
        const int my = dm[j];
        int r = 0;
        for (int t = 0; t < NS; ++t) {
            int v2 = dm[t];
            r += (v2 < my || (v2 == my && t < j)) ? 1 : 0;
        }
        perm[b * NS + r] = j;
        if (j >= NT) qpos[b * NG + (j - NT)] = r;
    }
}

// ---------------- build transformer input X (bf16, float4-vectorized, coalesced) ----------------
__global__ __launch_bounds__(256) void buildx_k(const float* __restrict__ featT,
        const float* __restrict__ queries, const int* __restrict__ perm,
        __hip_bfloat16* __restrict__ X)
{
    const int idx = blockIdx.x * 256 + threadIdx.x;    // NB*NS*(NDIN/4)
    if (idx >= NB * NS * (NDIN / 4)) return;
    const int dq = idx & 127;
    const int p = (idx >> 7) % NS;
    const int b = idx / (NS * 128);
    const int j = perm[b * NS + p];
    const float4* src = (j < NT)
        ? (const float4*)&featT[((size_t)(b * NT + j)) * NDIN]
        : (const float4*)&queries[((size_t)(b * NG + (j - NT))) * NDIN];
    float4 v = src[dq];
    short4 o;
    o.x = f2bfs(v.x); o.y = f2bfs(v.y); o.z = f2bfs(v.z); o.w = f2bfs(v.w);
    *(short4*)((short*)X + ((size_t)(b * NS + p)) * NDIN + dq * 4) = o;
}

// ---------------- W1 GEMM: 128x128 tile, 2-phase BK=32 dbuf prefetch, gelu, bf16 out -----------
__global__ __launch_bounds__(256) void bgemmw1_k(const __hip_bfloat16* __restrict__ A,
        const __hip_bfloat16* __restrict__ Bt, __hip_bfloat16* __restrict__ Cout,
        const float* __restrict__ bias, int M, int N, int K)
{
    __shared__ __align__(16) short SM[4][128 * 32];   // A0/A1/B0/B1 (BK=32 dbuf); epilogue reuse
    const int tid = threadIdx.x;
    const int wave = tid >> 6, lane = tid & 63;
    const int quad = lane >> 4, l16 = lane & 15;
    const int wm = wave >> 1, wn = wave & 1;
    int bx = blockIdx.x, by = blockIdx.y;
    swzxy(bx, by, gridDim.x, gridDim.y);
    const size_t bm = (size_t)by * 128, bn = (size_t)bx * 128;
    const int sw = (l16 >> 1) & 3;
    const short* Ag = (const short*)A;
    const short* Bg = (const short*)Bt;
    const int lrow = lane >> 2;
    const int lchunk = (lane & 3) ^ ((lane >> 3) & 3);
    const int rS = wave * 32;

    floatx4 acc[4][4];
#pragma unroll
    for (int i = 0; i < 4; ++i)
#pragma unroll
        for (int j = 0; j < 4; ++j) acc[i][j] = (floatx4){0.f, 0.f, 0.f, 0.f};

    {   // prologue: stage k0=0 into buffer 0
        const size_t ra = (bm + rS + lrow) * (size_t)K + lchunk * 8;
        const size_t rb = (bn + rS + lrow) * (size_t)K + lchunk * 8;
        gload_lds16(Ag + ra,                    &SM[0][rS * 32]);
        gload_lds16(Ag + ra + 16 * (size_t)K,   &SM[0][(rS + 16) * 32]);
        gload_lds16(Bg + rb,                    &SM[2][rS * 32]);
        gload_lds16(Bg + rb + 16 * (size_t)K,   &SM[2][(rS + 16) * 32]);
    }
    __syncthreads();
    int cur = 0;
    for (int k0 = 0; k0 < K; k0 += 32) {
        if (k0 + 32 < K) {
            const int nx = cur ^ 1;
            const size_t ra = (bm + rS + lrow) * (size_t)K + (k0 + 32) + lchunk * 8;
            const size_t rb = (bn + rS + lrow) * (size_t)K + (k0 + 32) + lchunk * 8;
            gload_lds16(Ag + ra,                  &SM[nx][rS * 32]);
            gload_lds16(Ag + ra + 16 * (size_t)K, &SM[nx][(rS + 16) * 32]);
            gload_lds16(Bg + rb,                  &SM[2 + nx][rS * 32]);
            gload_lds16(Bg + rb + 16 * (size_t)K, &SM[2 + nx][(rS + 16) * 32]);
        }
        shortx8 af[4], bf[4];
#pragma unroll
        for (int t = 0; t < 4; ++t) {
            af[t] = *(const shortx8*)&SM[cur][(wm * 64 + t * 16 + l16) * 32 + ((quad ^ sw) * 8)];
            bf[t] = *(const shortx8*)&SM[2 + cur][(wn * 64 + t * 16 + l16) * 32 + ((quad ^ sw) * 8)];
        }
#pragma unroll
        for (int mt = 0; mt < 4; ++mt)
#pragma unroll
            for (int nt = 0; nt < 4; ++nt)
                acc[mt][nt] = __builtin_amdgcn_mfma_f32_16x16x32_bf16(af[mt], bf[nt], acc[mt][nt], 0, 0, 0);
        __syncthreads();
        cur ^= 1;
    }
    // LDS-staged coalesced epilogue (per-wave region, intra-wave only); loop ended with barrier
    const size_t mbase = bm + wm * 64;
    const size_t nbase = bn + wn * 64;
    short* ep = &SM[wave][0];   // 4096 shorts = 64x64
#pragma unroll
    for (int nt = 0; nt < 4; ++nt) {
        const size_t n = nbase + nt * 16 + l16;
        const float bz = bias[n];
        const int col = nt * 16 + l16;
#pragma unroll
        for (int mt = 0; mt < 4; ++mt)
#pragma unroll
            for (int r = 0; r < 4; ++r) {
                const int rl = mt * 16 + quad * 4 + r;
                float e = gelu_f(acc[mt][nt][r] + bz);
                ep[rl * 64 + (((col >> 3) ^ (rl & 7)) * 8) + (col & 7)] = f2bfs(e);
            }
    }
    __asm__ __volatile__("" ::: "memory");
#pragma unroll
    for (int c2 = 0; c2 < 8; ++c2) {
        const int rl = c2 * 8 + (lane >> 3);
        const int cc = lane & 7;
        shortx8 v = *(const shortx8*)&ep[rl * 64 + ((cc ^ (rl & 7)) * 8)];
        *(shortx8*)((short*)Cout + (mbase + rl) * N + nbase + cc * 8) = v;
    }
}

// ---------------- QKV GEMM: fused RoPE + head-major + V-transpose, 2-phase BK=32 dbuf ----------
__global__ __launch_bounds__(256) void bgemmqkv_k(const __hip_bfloat16* __restrict__ A,
        const __hip_bfloat16* __restrict__ Bt, __hip_bfloat16* __restrict__ qh,
        __hip_bfloat16* __restrict__ kh, __hip_bfloat16* __restrict__ vT,
        const float2* __restrict__ tab)
{
    __shared__ __align__(16) short SM[4][128 * 32];
    const int tid = threadIdx.x;
    const int wave = tid >> 6, lane = tid & 63;
    const int quad = lane >> 4, l16 = lane & 15;
    const int wm = wave >> 1, wn = wave & 1;
    int bx = blockIdx.x, by = blockIdx.y;
    swzxy(bx, by, gridDim.x, gridDim.y);
    const size_t bm = (size_t)by * 128, bn = (size_t)bx * 128;
    const int sw = (l16 >> 1) & 3;
    const int K = 512;
    const short* Ag = (const short*)A;
    const short* Bg = (const short*)Bt;
    const int lrow = lane >> 2;
    const int lchunk = (lane & 3) ^ ((lane >> 3) & 3);
    const int rS = wave * 32;

    floatx4 acc[4][4];
#pragma unroll
    for (int i = 0; i < 4; ++i)
#pragma unroll
        for (int j = 0; j < 4; ++j) acc[i][j] = (floatx4){0.f, 0.f, 0.f, 0.f};

    {   // prologue
        const size_t ra = (bm + rS + lrow) * (size_t)K + lchunk * 8;
        const size_t rb = (bn + rS + lrow) * (size_t)K + lchunk * 8;
        gload_lds16(Ag + ra,                  &SM[0][rS * 32]);
        gload_lds16(Ag + ra + 16 * (size_t)K, &SM[0][(rS + 16) * 32]);
        gload_lds16(Bg + rb,                  &SM[2][rS * 32]);
        gload_lds16(Bg + rb + 16 * (size_t)K, &SM[2][(rS + 16) * 32]);
    }
    __syncthreads();
    int cur = 0;
    for (int k0 = 0; k0 < K; k0 += 32) {
        if (k0 + 32 < K) {
            const int nx = cur ^ 1;
            const size_t ra = (bm + rS + lrow) * (size_t)K + (k0 + 32) + lchunk * 8;
            const size_t rb = (bn + rS + lrow) * (size_t)K + (k0 + 32) + lchunk * 8;
            gload_lds16(Ag + ra,                  &SM[nx][rS * 32]);
            gload_lds16(Ag + ra + 16 * (size_t)K, &SM[nx][(rS + 16) * 32]);
            gload_lds16(Bg + rb,                  &SM[2 + nx][rS * 32]);
            gload_lds16(Bg + rb + 16 * (size_t)K, &SM[2 + nx][(rS + 16) * 32]);
        }
        shortx8 af[4], bf[4];
#pragma unroll
        for (int t = 0; t < 4; ++t) {
            af[t] = *(const shortx8*)&SM[cur][(wm * 64 + t * 16 + l16) * 32 + ((quad ^ sw) * 8)];
            bf[t] = *(const shortx8*)&SM[2 + cur][(wn * 64 + t * 16 + l16) * 32 + ((quad ^ sw) * 8)];
        }
#pragma unroll
        for (int mt = 0; mt < 4; ++mt)
#pragma unroll
            for (int nt = 0; nt < 4; ++nt)
                acc[mt][nt] = __builtin_amdgcn_mfma_f32_16x16x32_bf16(af[mt], bf[nt], acc[mt][nt], 0, 0, 0);
        __syncthreads();
        cur ^= 1;
    }
    short* ep = &SM[wave][0];
    const int bidx = (int)(bm / NS);
    const int sbase = (int)(bm - (size_t)bidx * NS) + wm * 64;
    const int region = (int)(bn >> 9);     // 0=q, 1=k, 2=v
    if (region < 2) {
        const float qsc = region ? 1.0f : 0.18033688011112043f;  // 0.125 * log2(e)
        const int h = (int)((((int)bn & 511) + wn * 64) >> 6);
        // stage rotated values as [s_local 64][d 64]
#pragma unroll
        for (int nt = 0; nt < 2; ++nt) {
            const int d1 = nt * 16 + l16, d2 = d1 + 32;
            const float2* tp = tab + d1;
#pragma unroll
            for (int mt = 0; mt < 4; ++mt)
#pragma unroll
                for (int r = 0; r < 4; ++r) {
                    const int sl = mt * 16 + quad * 4 + r;
                    const int s = sbase + sl;
                    float x1 = acc[mt][nt][r], x2 = acc[mt][nt + 2][r];
                    float2 cs = tp[s * 32];
                    ep[sl * 64 + (((d1 >> 3) ^ (sl & 7)) * 8) + (d1 & 7)] = f2bfs(qsc * (x1 * cs.x - x2 * cs.y));
                    ep[sl * 64 + (((d2 >> 3) ^ (sl & 7)) * 8) + (d2 & 7)] = f2bfs(qsc * (x1 * cs.y + x2 * cs.x));
                }
        }
        __asm__ __volatile__("" ::: "memory");
        short* dst = (short*)(region ? kh : qh) + ((size_t)(bidx * NH + h)) * NS * NDH;
#pragma unroll
        for (int c2 = 0; c2 < 8; ++c2) {
            const int sl = c2 * 8 + (lane >> 3);
            const int cc = lane & 7;
            shortx8 v = *(const shortx8*)&ep[sl * 64 + ((cc ^ (sl & 7)) * 8)];
            *(shortx8*)(dst + (size_t)(sbase + sl) * NDH + cc * 8) = v;
        }
    } else {
        const int base = (int)(bn - 1024) + wn * 64;
        const int h = base >> 6;
        // stage transposed [d_local 64][s_local 64]
#pragma unroll
        for (int nt = 0; nt < 4; ++nt) {
            const int dl = nt * 16 + l16;
#pragma unroll
            for (int mt = 0; mt < 4; ++mt)
#pragma unroll
                for (int r = 0; r < 4; ++r) {
                    const int sl = mt * 16 + quad * 4 + r;
                    ep[dl * 64 + (((sl >> 3) ^ (dl & 7)) * 8) + (sl & 7)] = f2bfs(acc[mt][nt][r]);
                }
        }
        __asm__ __volatile__("" ::: "memory");
        short* vp = (short*)vT + ((size_t)(bidx * NH + h)) * NDH * NS;
#pragma unroll
        for (int c2 = 0; c2 < 8; ++c2) {
            const int dl = c2 * 8 + (lane >> 3);
            const int cc = lane & 7;
            shortx8 v = *(const shortx8*)&ep[dl * 64 + ((cc ^ (dl & 7)) * 8)];
            *(shortx8*)(vp + (size_t)dl * NS + sbase + cc * 8) = v;
        }
    }
}

// ---------------- bf16 MFMA GEMM 64x128 tile, 2-phase BK=32 dbuf (N=512 shapes) ----------------
// EPI 0: acc+bias?  EPI 2: res + ls*(acc+bias?)  EPI 4: masked transposed writeout (W_out)
template <int EPI>
__global__ __launch_bounds__(256) void bgemm64_k(const __hip_bfloat16* __restrict__ A,
        const __hip_bfloat16* __restrict__ Bt, void* __restrict__ Cout,
        const float* __restrict__ bias, const float* __restrict__ ls,
        const float* __restrict__ res, const int* __restrict__ nsegp, int M, int N, int K)
{
    __shared__ __align__(16) short As[2][64 * 32];    //  8 KB
    __shared__ __align__(16) short Bs[2][128 * 32];   // 16 KB
    const int tid = threadIdx.x;
    const int wave = tid >> 6, lane = tid & 63;
    const int quad = lane >> 4, l16 = lane & 15;
    const int wm = wave >> 1, wn = wave & 1;
    int bx = blockIdx.x, by = blockIdx.y;
    swzxy(bx, by, gridDim.x, gridDim.y);
    const size_t bm = (size_t)by * 64, bn = (size_t)bx * 128;
    const int sw = (l16 >> 1) & 3;
    const short* Ag = (const short*)A;
    const short* Bg = (const short*)Bt;
    const int lrow = lane >> 2;
    const int lchunk = (lane & 3) ^ ((lane >> 3) & 3);
    const int rA = wave * 16, rB = wave * 32;

    floatx4 acc[2][4];
#pragma unroll
    for (int i = 0; i < 2; ++i)
#pragma unroll
        for (int j = 0; j < 4; ++j) acc[i][j] = (floatx4){0.f, 0.f, 0.f, 0.f};

    {   // prologue: stage k0=0 into buffer 0
        const size_t ra = (bm + rA + lrow) * (size_t)K + lchunk * 8;
        const size_t rb = (bn + rB + lrow) * (size_t)K + lchunk * 8;
        gload_lds16(Ag + ra,                  &As[0][rA * 32]);
        gload_lds16(Bg + rb,                  &Bs[0][rB * 32]);
        gload_lds16(Bg + rb + 16 * (size_t)K, &Bs[0][(rB + 16) * 32]);
    }
    __syncthreads();
    int cur = 0;
    for (int k0 = 0; k0 < K; k0 += 32) {
        if (k0 + 32 < K) {
            const int nx = cur ^ 1;
            const size_t ra = (bm + rA + lrow) * (size_t)K + (k0 + 32) + lchunk * 8;
            const size_t rb = (bn + rB + lrow) * (size_t)K + (k0 + 32) + lchunk * 8;
            gload_lds16(Ag + ra,                  &As[nx][rA * 32]);
            gload_lds16(Bg + rb,                  &Bs[nx][rB * 32]);
            gload_lds16(Bg + rb + 16 * (size_t)K, &Bs[nx][(rB + 16) * 32]);
        }
        shortx8 af[2], bf[4];
#pragma unroll
        for (int t = 0; t < 2; ++t)
            af[t] = *(const shortx8*)&As[cur][(wm * 32 + t * 16 + l16) * 32 + ((quad ^ sw) * 8)];
#pragma unroll
        for (int t = 0; t < 4; ++t)
            bf[t] = *(const shortx8*)&Bs[cur][(wn * 64 + t * 16 + l16) * 32 + ((quad ^ sw) * 8)];
#pragma unroll
        for (int mt = 0; mt < 2; ++mt)
#pragma unroll
            for (int nt = 0; nt < 4; ++nt)
                acc[mt][nt] = __builtin_amdgcn_mfma_f32_16x16x32_bf16(af[mt], bf[nt], acc[mt][nt], 0, 0, 0);
        __syncthreads();
        cur ^= 1;
    }
    const size_t mbase = bm + wm * 32;
    const size_t nbase = bn + wn * 64;
#pragma unroll
    for (int nt = 0; nt < 4; ++nt) {
        const size_t n = nbase + nt * 16 + l16;
        const float bz = bias ? bias[n] : 0.f;
        const float lz = (EPI == 2) ? ls[n] : 0.f;
#pragma unroll
        for (int mt = 0; mt < 2; ++mt) {
#pragma unroll
            for (int r = 0; r < 4; ++r) {
                const size_t m = mbase + mt * 16 + quad * 4 + r;
                float e = acc[mt][nt][r] + bz;
                if (EPI == 4) {
                    const int b = (int)(m >> 7), g = (int)(m & 127);
                    float val = (g < nsegp[b]) ? e : 0.0f;
                    ((float*)Cout)[(size_t)b * (NDIN * NG) + n * NG + g] = val;
                } else {
                    const size_t off = m * N + n;
                    if (EPI == 2) e = res[off] + lz * e;
                    ((float*)Cout)[off] = e;
                }
            }
        }
    }
}

// ---------------- wave-per-row LayerNorm, 4 rows/block (fp32 in -> bf16 out) ----------------
__global__ __launch_bounds__(256) void lnw_k(const float* __restrict__ in,
        __hip_bfloat16* __restrict__ out, const float* __restrict__ gam, const float* __restrict__ bet)
{
    const int r = blockIdx.x * 4 + (threadIdx.x >> 6);
    const int t = threadIdx.x & 63;
    const float4* xp = (const float4*)(in + (size_t)r * NDM);
    float4 a = xp[t * 2], b4 = xp[t * 2 + 1];
    float s = a.x + a.y + a.z + a.w + b4.x + b4.y + b4.z + b4.w;
#pragma unroll
    for (int o = 1; o < 64; o <<= 1) s += __shfl_xor(s, o);
    const float mean = s * (1.0f / NDM);
    float dx[8] = {a.x - mean, a.y - mean, a.z - mean, a.w - mean,
                   b4.x - mean, b4.y - mean, b4.z - mean, b4.w - mean};
    float v = 0.f;
#pragma unroll
    for (int i = 0; i < 8; ++i) v += dx[i] * dx[i];
#pragma unroll
    for (int o = 1; o < 64; o <<= 1) v += __shfl_xor(v, o);
    const float inv = rsqrtf(v * (1.0f / NDM) + 1e-5f);
    const float4* gp = (const float4*)gam;
    const float4* bp = (const float4*)bet;
    float4 g0 = gp[t * 2], g1 = gp[t * 2 + 1], q0 = bp[t * 2], q1 = bp[t * 2 + 1];
    shortx8 o8;
    o8[0] = f2bfs(dx[0] * inv * g0.x + q0.x);
    o8[1] = f2bfs(dx[1] * inv * g0.y + q0.y);
    o8[2] = f2bfs(dx[2] * inv * g0.z + q0.z);
    o8[3] = f2bfs(dx[3] * inv * g0.w + q0.w);
    o8[4] = f2bfs(dx[4] * inv * g1.x + q1.x);
    o8[5] = f2bfs(dx[5] * inv * g1.y + q1.y);
    o8[6] = f2bfs(dx[6] * inv * g1.z + q1.z);
    o8[7] = f2bfs(dx[7] * inv * g1.w + q1.w);
    *(shortx8*)((short*)out + (size_t)r * NDM + t * 8) = o8;
}

// ---------------- wave-per-row final LN over gathered query rows ----------------
__global__ __launch_bounds__(64) void lnwg_k(const float* __restrict__ h,
        __hip_bfloat16* __restrict__ out, const float* __restrict__ gam, const float* __restrict__ bet,
        const int* __restrict__ qpos)
{
    const int r = blockIdx.x, t = threadIdx.x;   // r = b*NG + g
    const int b = r >> 7;
    const int src = qpos[r];
    const float4* xp = (const float4*)(h + ((size_t)(b * NS + src)) * NDM);
    float4 a = xp[t * 2], b4 = xp[t * 2 + 1];
    float s = a.x + a.y + a.z + a.w + b4.x + b4.y + b4.z + b4.w;
#pragma unroll
    for (int o = 1; o < 64; o <<= 1) s += __shfl_xor(s, o);
    const float mean = s * (1.0f / NDM);
    float dx[8] = {a.x - mean, a.y - mean, a.z - mean, a.w - mean,
                   b4.x - mean, b4.y - mean, b4.z - mean, b4.w - mean};
    float v = 0.f;
#pragma unroll
    for (int i = 0; i < 8; ++i) v += dx[i] * dx[i];
#pragma unroll
    for (int o = 1; o < 64; o <<= 1) v += __shfl_xor(v, o);
    const float inv = rsqrtf(v * (1.0f / NDM) + 1e-5f);
    const float4* gp = (const float4*)gam;
    const float4* bp = (const float4*)bet;
    float4 g0 = gp[t * 2], g1 = gp[t * 2 + 1], q0 = bp[t * 2], q1 = bp[t * 2 + 1];
    shortx8 o8;
    o8[0] = f2bfs(dx[0] * inv * g0.x + q0.x);
    o8[1] = f2bfs(dx[1] * inv * g0.y + q0.y);
    o8[2] = f2bfs(dx[2] * inv * g0.z + q0.z);
    o8[3] = f2bfs(dx[3] * inv * g0.w + q0.w);
    o8[4] = f2bfs(dx[4] * inv * g1.x + q1.x);
    o8[5] = f2bfs(dx[5] * inv * g1.y + q1.y);
    o8[6] = f2bfs(dx[6] * inv * g1.z + q1.z);
    o8[7] = f2bfs(dx[7] * inv * g1.w + q1.w);
    *(shortx8*)((short*)out + (size_t)r * NDM + t * 8) = o8;
}

// ---------------- flash attention v12: QBLK=128, 8 waves — staging amortized 2x ----------------
// [R8 measured best: total 601.7 µs, fattn 54.4 µs, occupancy 31.6%.] v13's 32-q/wave variant
// halved chip-wide wave count and regressed (occupancy 12.9%, 62.7 µs) — attention here is
// latency-bound and TLP-fed; ~54 µs is the structural floor of this decomposition.
#define FKT 64
#define FKP 68
#define NTL (NS / FKT)   // 18
#define QB  128
__global__ __launch_bounds__(512) void fattn_k(const __hip_bfloat16* __restrict__ qb,
        const __hip_bfloat16* __restrict__ kb, const __hip_bfloat16* __restrict__ vbT,
        __hip_bfloat16* __restrict__ o)
{
    __shared__ __align__(16) short Ks[FKT * FKP];   //  8704 B
    __shared__ __align__(16) short Vt[NDH * FKP];   //  8704 B
    __shared__ __align__(16) short Pl[QB * FKP];    // 17408 B
    const int tid = threadIdx.x;
    const int wave = tid >> 6, lane = tid & 63;
    const int quad = lane >> 4, l16 = lane & 15;
    const int L = blockIdx.x;                 // 576 = 8 xcd * 8 bh-low * 9 qblk
    const int xcd = L & 7, sl = L >> 3;       // sl in 0..71
    const int bh = (xcd << 3) | (sl & 7);
    const int q0 = (sl >> 3) * QB;            // 0..8 * 128
    const int bb = bh >> 3, hh = bh & 7;
    const short* qbase = (const short*)qb + (size_t)bh * NS * NDH;
    const short* kbase = (const short*)kb + (size_t)bh * NS * NDH;
    const short* vbase = (const short*)vbT + (size_t)bh * NDH * NS;

    shortx8 Qf0, Qf1;
    {
        const short* qp = qbase + (size_t)(q0 + wave * 16 + l16) * NDH + quad * 8;
        Qf0 = *(const shortx8*)qp;
        Qf1 = *(const shortx8*)(qp + 32);
    }
    shortx8 Of;                       // all-ones bf16 B-fragment for the denominator MFMA
#pragma unroll
    for (int i = 0; i < 8; ++i) Of[i] = 0x3F80;

    floatx4 Oacc[4];
#pragma unroll
    for (int i = 0; i < 4; ++i) Oacc[i] = (floatx4){0.f, 0.f, 0.f, 0.f};
    floatx4 Oacc5 = (floatx4){0.f, 0.f, 0.f, 0.f};   // l = sum_k P (all cols equal)

    const int sr = tid >> 3, sc = (tid & 7) * 8;     // 512 threads cover 64x64 once
    const int prow = wave * 16 + l16;                // 0..127, per-wave-private rows
    const short* kg = kbase + (size_t)sr * NDH + sc;
    const short* vg = vbase + (size_t)sr * NS + sc;
    shortx8 pk = *(const shortx8*)kg;
    shortx8 pv = *(const shortx8*)vg;

    for (int t = 0; t < NTL; ++t) {
        __syncthreads();
        *(shortx8*)&Ks[sr * FKP + sc] = pk;
        *(shortx8*)&Vt[sr * FKP + sc] = pv;
        __syncthreads();
        if (t + 1 < NTL) {
            kg += FKT * NDH; vg += FKT;
            pk = *(const shortx8*)kg;
            pv = *(const shortx8*)vg;
        }

        // S^T[key][q] = K Q^T  (Q pre-scaled by 0.125*log2e -> exp2 domain)
        floatx4 S[4];
#pragma unroll
        for (int kbk = 0; kbk < 4; ++kbk) {
            shortx8 kf0 = *(const shortx8*)&Ks[(kbk * 16 + l16) * FKP + quad * 8];
            shortx8 kf1 = *(const shortx8*)&Ks[(kbk * 16 + l16) * FKP + 32 + quad * 8];
            floatx4 sa = (floatx4){0.f, 0.f, 0.f, 0.f};
            sa = __builtin_amdgcn_mfma_f32_16x16x32_bf16(kf0, Qf0, sa, 0, 0, 0);
            sa = __builtin_amdgcn_mfma_f32_16x16x32_bf16(kf1, Qf1, sa, 0, 0, 0);
            S[kbk] = sa;
        }
        // no-max softmax numerators; RTZ pack (bias cancels in num/denom ratio)
#pragma unroll
        for (int kbk = 0; kbk < 4; ++kbk) {
            uint2 u;
            u.x = pack_bf2_rz(exp2f(S[kbk][0]), exp2f(S[kbk][1]));
            u.y = pack_bf2_rz(exp2f(S[kbk][2]), exp2f(S[kbk][3]));
            *(uint2*)&Pl[prow * FKP + kbk * 16 + quad * 4] = u;
        }
        __asm__ __volatile__("" ::: "memory");   // P rows are wave-private: no barrier needed
        shortx8 Pf0 = *(const shortx8*)&Pl[prow * FKP + quad * 8];
        shortx8 Pf1 = *(const shortx8*)&Pl[prow * FKP + 32 + quad * 8];
        __builtin_amdgcn_s_setprio(1);
#pragma unroll
        for (int ct = 0; ct < 4; ++ct) {
            shortx8 vf0 = *(const shortx8*)&Vt[(ct * 16 + l16) * FKP + quad * 8];
            shortx8 vf1 = *(const shortx8*)&Vt[(ct * 16 + l16) * FKP + 32 + quad * 8];
            Oacc[ct] = __builtin_amdgcn_mfma_f32_16x16x32_bf16(Pf0, vf0, Oacc[ct], 0, 0, 0);
            Oacc[ct] = __builtin_amdgcn_mfma_f32_16x16x32_bf16(Pf1, vf1, Oacc[ct], 0, 0, 0);
        }
        Oacc5 = __builtin_amdgcn_mfma_f32_16x16x32_bf16(Pf0, Of, Oacc5, 0, 0, 0);
        Oacc5 = __builtin_amdgcn_mfma_f32_16x16x32_bf16(Pf1, Of, Oacc5, 0, 0, 0);
        __builtin_amdgcn_s_setprio(0);
    }
#pragma unroll
    for (int i = 0; i < 4; ++i) {
        // Oacc5 columns are all equal (B = ones): lane's own value IS its row's denominator
        const float inv = 1.0f / Oacc5[i];
        const int row = q0 + wave * 16 + quad * 4 + i;
        __hip_bfloat16* op = o + ((size_t)(bb * NS + row)) * NDM + hh * NDH + l16;
        op[0]  = __float2bfloat16(Oacc[0][i] * inv);
        op[16] = __float2bfloat16(Oacc[1][i] * inv);
        op[32] = __float2bfloat16(Oacc[2][i] * inv);
        op[48] = __float2bfloat16(Oacc[3][i] * inv);
    }
}

extern "C" void kernel_launch(void* const* d_in, const int* in_sizes, int n_in,
                              void* d_out, int out_size, void* d_ws, size_t ws_size,
                              hipStream_t stream) {
    const float* features = (const float*)d_in[0];
    const float* align    = (const float*)d_in[1];
    const int*   nseg     = (const int*)d_in[2];
    const float* W_in  = (const float*)d_in[3];
    const float* b_in  = (const float*)d_in[4];
    const float* ln1_s = (const float*)d_in[5];
    const float* ln1_b = (const float*)d_in[6];
    const float* Wq = (const float*)d_in[7];
    const float* Wk = (const float*)d_in[8];
    const float* Wv = (const float*)d_in[9];
    const float* Wo = (const float*)d_in[10];
    const float* ls1   = (const float*)d_in[11];
    const float* ln2_s = (const float*)d_in[12];
    const float* ln2_b = (const float*)d_in[13];
    const float* W1 = (const float*)d_in[14];
    const float* b1 = (const float*)d_in[15];
    const float* W2 = (const float*)d_in[16];
    const float* b2 = (const float*)d_in[17];
    const float* ls2   = (const float*)d_in[18];
    const float* lnf_s = (const float*)d_in[19];
    const float* lnf_b = (const float*)d_in[20];
    const float* W_out = (const float*)d_in[21];
    const float* b_out = (const float*)d_in[22];

    const size_t SZ_BSD = (size_t)NB * NS * NDM;      // 4,718,592

    // ---- workspace map: weights & index arrays FIRST, then activations ----
    float* p = (float*)d_ws;
    __hip_bfloat16* w_inT  = (__hip_bfloat16*)p;
    __hip_bfloat16* wqkvT0 = w_inT + 512 * 512;
    __hip_bfloat16* wqkvT1 = wqkvT0 + 1536 * 512;
    __hip_bfloat16* woT0   = wqkvT1 + 1536 * 512;
    __hip_bfloat16* woT1   = woT0 + 512 * 512;
    __hip_bfloat16* w1T0   = woT1 + 512 * 512;
    __hip_bfloat16* w1T1   = w1T0 + 2048 * 512;
    __hip_bfloat16* w2T0   = w1T1 + 2048 * 512;
    __hip_bfloat16* w2T1   = w2T0 + 512 * 2048;
    __hip_bfloat16* woutT  = w2T1 + 512 * 2048;
    int* glast = (int*)(woutT + 512 * 512);
    int* perm  = glast + NB * NG;
    int* qpos  = perm + NB * NS;
    float2* ropetab = (float2*)(qpos + NB * NG);       // 36864 float2
    p = (float*)(ropetab + NS * 32);

    float* featT = p; p += (size_t)NB * NT * NDIN;                      // fp32 [b][t][d]
    float* hbuf = p; p += SZ_BSD;                                       // fp32 residual
    __hip_bfloat16* ybuf = (__hip_bfloat16*)p;  p += SZ_BSD / 2;        // bf16 LN out
    __hip_bfloat16* obuf = (__hip_bfloat16*)p;  p += SZ_BSD / 2;        // bf16 attn out
    __hip_bfloat16* ubuf = (__hip_bfloat16*)p;  p += SZ_BSD * 2;        // bf16 [9216][2048]; also qh+kh
    __hip_bfloat16* xin  = (__hip_bfloat16*)p;  p += SZ_BSD / 2;        // bf16 X; also vT
    float* quer = p; p += (size_t)NB * NG * NDIN;
    __hip_bfloat16* hq = (__hip_bfloat16*)p; p += (size_t)NB * NG * NDM / 2;
    const size_t needed = (size_t)((char*)p - (char*)d_ws);
    if (ws_size < needed) return;

    __hip_bfloat16* qh = ubuf;
    __hip_bfloat16* kh = ubuf + SZ_BSD;
    __hip_bfloat16* vT = xin;

    // ---- prep (merged: ropetab + ftrans + weight transposes in one dispatch) ----
    prep0_k<<<144 + 4096 + 6656, 256, 0, stream>>>(ropetab, features, featT,
            W_in, Wq, Wk, Wv, Wo, W1, W2, W_out,
            w_inT, wqkvT0, wqkvT1, woT0, woT1, w1T0, w1T1, w2T0, w2T1, woutT);
    pool_k<<<NB * NG, 256, 0, stream>>>(align, featT, glast, quer);
    rank_k<<<dim3((NS + 255) / 256, NB), 256, 0, stream>>>(glast, nseg, perm, qpos);
    buildx_k<<<(NB * NS * (NDIN / 4) + 255) / 256, 256, 0, stream>>>(featT, quer, perm, xin);

    const int M = NB * NS;   // 9216
    bgemm64_k<0><<<dim3(NDM / 128, M / 64), 256, 0, stream>>>(xin, w_inT, hbuf, b_in, nullptr, nullptr, nullptr, M, NDM, NDIN);

    for (int l = 0; l < NL; ++l) {
        __hip_bfloat16* wqkvT = (l ? wqkvT1 : wqkvT0);
        __hip_bfloat16* woT   = (l ? woT1 : woT0);
        __hip_bfloat16* w1T   = (l ? w1T1 : w1T0);
        __hip_bfloat16* w2T   = (l ? w2T1 : w2T0);

        lnw_k<<<M / 4, 256, 0, stream>>>(hbuf, ybuf, ln1_s + l * NDM, ln1_b + l * NDM);
        bgemmqkv_k<<<dim3(1536 / 128, M / 128), 256, 0, stream>>>(ybuf, wqkvT, qh, kh, vT, ropetab);
        fattn_k<<<(NS / QB) * NH * NB, 512, 0, stream>>>(qh, kh, vT, obuf);
        bgemm64_k<2><<<dim3(NDM / 128, M / 64), 256, 0, stream>>>(obuf, woT, hbuf, nullptr, ls1 + l * NDM, hbuf, nullptr, M, NDM, NDM);
        lnw_k<<<M / 4, 256, 0, stream>>>(hbuf, ybuf, ln2_s + l * NDM, ln2_b + l * NDM);
        bgemmw1_k<<<dim3(NFF / 128, M / 128), 256, 0, stream>>>(ybuf, w1T, ubuf, b1 + l * NFF, M, NFF, NDM);
        bgemm64_k<2><<<dim3(NDM / 128, M / 64), 256, 0, stream>>>(ubuf, w2T, hbuf, b2 + l * NDM, ls2 + l * NDM, hbuf, nullptr, M, NDM, NFF);
    }

    lnwg_k<<<NB * NG, 64, 0, stream>>>(hbuf, hq, lnf_s, lnf_b, qpos);
    bgemm64_k<4><<<dim3(NDIN / 128, (NB * NG) / 64), 256, 0, stream>>>(hq, woutT, d_out, b_out, nullptr, nullptr, nseg, NB * NG, NDIN, NDM);
}